// Round 3
// baseline (140.789 us; speedup 1.0000x reference)
//
#include <hip/hip_runtime.h>
#include <math.h>

#define NS 4
#define HDIM 1024
#define DDIM 4096           // NS*HDIM
#define MDIM 24             // (2+NS)*NS
#define T 4                 // tokens per block
#define NTH 256
#define HC_EPS_F 1e-6f
#define NORM_EPS_F 1e-6f

__launch_bounds__(NTH, 3)
__global__ void mhc_fused(const float* __restrict__ x,
                          const float* __restrict__ hc_fn,
                          const float* __restrict__ hc_scale,
                          const float* __restrict__ hc_base,
                          float* __restrict__ out) {
  __shared__ float w_s[MDIM][T];
  __shared__ float ss_s[T];
  __shared__ float hpre_s[T][NS];
  __shared__ float hpost_s[T][NS];
  __shared__ float hres_s[T][NS][NS];

  const int tid  = threadIdx.x;
  const int lane = tid & 63;
  const int wave = tid >> 6;
  const long long tok0 = (long long)blockIdx.x * T;

  const float4* xb[T];
  #pragma unroll
  for (int tt = 0; tt < T; ++tt)
    xb[tt] = (const float4*)(x + (tok0 + tt) * DDIM);

  // ---- Phase B: 24 dots + sumsq, straight from global (L1/L2-cached).
  //      Wave w owns m in [6w, 6w+6). Manual double-buffer prefetch. ----
  const int mb = wave * 6;
  const float4* fn4[6];
  #pragma unroll
  for (int m = 0; m < 6; ++m)
    fn4[m] = (const float4*)(hc_fn + (long long)(mb + m) * DDIM);

  float acc[6][T];
  float ssq[T];
  #pragma unroll
  for (int m = 0; m < 6; ++m)
    #pragma unroll
    for (int tt = 0; tt < T; ++tt) acc[m][tt] = 0.f;
  #pragma unroll
  for (int tt = 0; tt < T; ++tt) ssq[tt] = 0.f;

  float4 c_fn[6], c_xv[T];
  #pragma unroll
  for (int m = 0; m < 6; ++m) c_fn[m] = fn4[m][lane];
  #pragma unroll
  for (int tt = 0; tt < T; ++tt) c_xv[tt] = xb[tt][lane];

  #pragma unroll 2
  for (int it = 0; it < 16; ++it) {
    float4 n_fn[6], n_xv[T];
    if (it < 15) {
      const int nfl = (it + 1) * 64 + lane;
      #pragma unroll
      for (int m = 0; m < 6; ++m) n_fn[m] = fn4[m][nfl];
      #pragma unroll
      for (int tt = 0; tt < T; ++tt) n_xv[tt] = xb[tt][nfl];
    }
    #pragma unroll
    for (int tt = 0; tt < T; ++tt) {
      const float4 xv = c_xv[tt];
      ssq[tt] = fmaf(xv.x, xv.x, fmaf(xv.y, xv.y, fmaf(xv.z, xv.z, fmaf(xv.w, xv.w, ssq[tt]))));
      #pragma unroll
      for (int m = 0; m < 6; ++m)
        acc[m][tt] = fmaf(xv.x, c_fn[m].x,
                     fmaf(xv.y, c_fn[m].y,
                     fmaf(xv.z, c_fn[m].z,
                     fmaf(xv.w, c_fn[m].w, acc[m][tt]))));
    }
    #pragma unroll
    for (int m = 0; m < 6; ++m) c_fn[m] = n_fn[m];
    #pragma unroll
    for (int tt = 0; tt < T; ++tt) c_xv[tt] = n_xv[tt];
  }

  // ---- cross-lane reduction of the 24 partials (+ sumsq from wave 0) ----
  #pragma unroll
  for (int m = 0; m < 6; ++m)
    #pragma unroll
    for (int tt = 0; tt < T; ++tt) {
      float v = acc[m][tt];
      #pragma unroll
      for (int off = 32; off > 0; off >>= 1) v += __shfl_xor(v, off, 64);
      if (lane == 0) w_s[mb + m][tt] = v;
    }
  if (wave == 0) {
    #pragma unroll
    for (int tt = 0; tt < T; ++tt) {
      float v = ssq[tt];
      #pragma unroll
      for (int off = 32; off > 0; off >>= 1) v += __shfl_xor(v, off, 64);
      if (lane == 0) ss_s[tt] = v;
    }
  }
  __syncthreads();

  // ---- Phase C: gates + sinkhorn, fully in-lane; lane tt owns token tt ----
  if (wave == 0 && lane < T) {
    const int tt = lane;
    const float rs = rsqrtf(ss_s[tt] * (1.0f / DDIM) + NORM_EPS_F);
    const float s0 = hc_scale[0];
    const float s1 = hc_scale[1];
    const float s2 = hc_scale[2];

    float h[NS][NS];
    #pragma unroll
    for (int i = 0; i < NS; ++i)
      #pragma unroll
      for (int j = 0; j < NS; ++j)
        h[i][j] = w_s[8 + i * NS + j][tt] * rs * s2 + hc_base[8 + i * NS + j];

    // softmax over j (per row) + eps
    #pragma unroll
    for (int i = 0; i < NS; ++i) {
      float mx = fmaxf(fmaxf(h[i][0], h[i][1]), fmaxf(h[i][2], h[i][3]));
      float e0 = expf(h[i][0] - mx), e1 = expf(h[i][1] - mx);
      float e2 = expf(h[i][2] - mx), e3 = expf(h[i][3] - mx);
      float s = e0 + e1 + e2 + e3;
      h[i][0] = e0 / s + HC_EPS_F;
      h[i][1] = e1 / s + HC_EPS_F;
      h[i][2] = e2 / s + HC_EPS_F;
      h[i][3] = e3 / s + HC_EPS_F;
    }
    // column normalize
    #pragma unroll
    for (int j = 0; j < NS; ++j) {
      float cs = h[0][j] + h[1][j] + h[2][j] + h[3][j] + HC_EPS_F;
      #pragma unroll
      for (int i = 0; i < NS; ++i) h[i][j] /= cs;
    }
    for (int itn = 0; itn < 19; ++itn) {
      #pragma unroll
      for (int i = 0; i < NS; ++i) {
        float rsum = h[i][0] + h[i][1] + h[i][2] + h[i][3] + HC_EPS_F;
        #pragma unroll
        for (int j = 0; j < NS; ++j) h[i][j] /= rsum;
      }
      #pragma unroll
      for (int j = 0; j < NS; ++j) {
        float cs = h[0][j] + h[1][j] + h[2][j] + h[3][j] + HC_EPS_F;
        #pragma unroll
        for (int i = 0; i < NS; ++i) h[i][j] /= cs;
      }
    }
    #pragma unroll
    for (int i = 0; i < NS; ++i)
      #pragma unroll
      for (int j = 0; j < NS; ++j) hres_s[tt][i][j] = h[i][j];

    #pragma unroll
    for (int e = 0; e < NS; ++e) {
      const float wp = w_s[e][tt] * rs;
      hpre_s[tt][e] = 1.0f / (1.0f + expf(-(wp * s0 + hc_base[e]))) + HC_EPS_F;
      const float wq = w_s[NS + e][tt] * rs;
      hpost_s[tt][e] = 2.0f / (1.0f + expf(-(wq * s1 + hc_base[NS + e])));
    }
  }
  __syncthreads();

  // ---- Phase D: out[tt][n][h] = h_post[n]*y[h] + sum_i h_res[i][n]*x[i][h]
  //      y[h] = sum_i h_pre[i]*x[i][h]; x re-read from global (L2-hot) ----
  #pragma unroll
  for (int tt = 0; tt < T; ++tt) {
    float hp[NS], hq[NS], hr[NS][NS];
    #pragma unroll
    for (int i = 0; i < NS; ++i) {
      hp[i] = hpre_s[tt][i];
      hq[i] = hpost_s[tt][i];
      #pragma unroll
      for (int j = 0; j < NS; ++j) hr[i][j] = hres_s[tt][i][j];
    }
    float4 xv[4];
    #pragma unroll
    for (int p = 0; p < 4; ++p) xv[p] = xb[tt][p * NTH + tid];

    float4 y;
    y.x = hp[0]*xv[0].x + hp[1]*xv[1].x + hp[2]*xv[2].x + hp[3]*xv[3].x;
    y.y = hp[0]*xv[0].y + hp[1]*xv[1].y + hp[2]*xv[2].y + hp[3]*xv[3].y;
    y.z = hp[0]*xv[0].z + hp[1]*xv[1].z + hp[2]*xv[2].z + hp[3]*xv[3].z;
    y.w = hp[0]*xv[0].w + hp[1]*xv[1].w + hp[2]*xv[2].w + hp[3]*xv[3].w;
    #pragma unroll
    for (int n = 0; n < NS; ++n) {
      float4 o;
      o.x = hq[n]*y.x + hr[0][n]*xv[0].x + hr[1][n]*xv[1].x + hr[2][n]*xv[2].x + hr[3][n]*xv[3].x;
      o.y = hq[n]*y.y + hr[0][n]*xv[0].y + hr[1][n]*xv[1].y + hr[2][n]*xv[2].y + hr[3][n]*xv[3].y;
      o.z = hq[n]*y.z + hr[0][n]*xv[0].z + hr[1][n]*xv[1].z + hr[2][n]*xv[2].z + hr[3][n]*xv[3].z;
      o.w = hq[n]*y.w + hr[0][n]*xv[0].w + hr[1][n]*xv[1].w + hr[2][n]*xv[2].w + hr[3][n]*xv[3].w;
      ((float4*)(out + ((tok0 + tt) * NS + n) * HDIM))[tid] = o;
    }
  }
}

extern "C" void kernel_launch(void* const* d_in, const int* in_sizes, int n_in,
                              void* d_out, int out_size, void* d_ws, size_t ws_size,
                              hipStream_t stream) {
  const float* x        = (const float*)d_in[0];
  const float* hc_fn    = (const float*)d_in[1];
  const float* hc_scale = (const float*)d_in[2];
  const float* hc_base  = (const float*)d_in[3];
  float* out = (float*)d_out;

  const int ntok = in_sizes[0] / DDIM;   // B*S = 8192
  const int grid = ntok / T;             // 2048
  mhc_fused<<<grid, NTH, 0, stream>>>(x, hc_fn, hc_scale, hc_base, out);
}

// Round 4
// 112.810 us; speedup vs baseline: 1.2480x; 1.2480x over previous
//
#include <hip/hip_runtime.h>
#include <math.h>

#define NS 4
#define HDIM 1024
#define DDIM 4096           // NS*HDIM
#define MDIM 24             // (2+NS)*NS
#define T 4                 // tokens per block
#define NTH 512             // 8 waves
#define HC_EPS_F 1e-6f
#define NORM_EPS_F 1e-6f

__device__ __forceinline__ void gload_lds16(const float* g, float* l) {
  __builtin_amdgcn_global_load_lds(
      (const __attribute__((address_space(1))) void*)g,
      (__attribute__((address_space(3))) void*)l, 16, 0, 0);
}
__device__ __forceinline__ float frcp(float v) { return __builtin_amdgcn_rcpf(v); }

__launch_bounds__(NTH, 4)
__global__ void mhc_fused(const float* __restrict__ x,
                          const float* __restrict__ hc_fn,
                          const float* __restrict__ hc_scale,
                          const float* __restrict__ hc_base,
                          float* __restrict__ out) {
  __shared__ float xs[T * DDIM];       // 64 KB: x for 4 tokens
  __shared__ float w_s[MDIM][T];
  __shared__ float ss_s[T];
  __shared__ float hpre_s[T][NS];
  __shared__ float hpost_s[T][NS];
  __shared__ float hres_s[T][NS][NS];

  const int tid  = threadIdx.x;
  const int lane = tid & 63;
  const int wave = tid >> 6;
  const long long tok0 = (long long)blockIdx.x * T;
  const float* xg = x + tok0 * DDIM;

  // ---- Phase A: async-stage 64 KB of x. Each (c,wave) covers a contiguous
  //      64-float4 run: LDS dst = uniform base + lane*16. ----
  #pragma unroll
  for (int c = 0; c < 8; ++c)
    gload_lds16(xg + (c * NTH + tid) * 4, xs + (c * NTH + wave * 64) * 4);

  // hc_fn prefetch issued BEFORE the barrier (independent of LDS)
  const int mb = wave * 3;             // wave owns m in [3w, 3w+3)
  const float4* fn4[3];
  #pragma unroll
  for (int m = 0; m < 3; ++m)
    fn4[m] = (const float4*)(hc_fn + (long long)(mb + m) * DDIM);
  float4 c_fn[3];
  #pragma unroll
  for (int m = 0; m < 3; ++m) c_fn[m] = fn4[m][lane];

  __syncthreads();                     // drains staging vmcnt

  // ---- Phase B: 3 dots/wave (+ ssq on wave 7) over LDS x, 1-deep prefetch ----
  float acc[3][T];
  float ssq[T];
  #pragma unroll
  for (int m = 0; m < 3; ++m)
    #pragma unroll
    for (int tt = 0; tt < T; ++tt) acc[m][tt] = 0.f;
  #pragma unroll
  for (int tt = 0; tt < T; ++tt) ssq[tt] = 0.f;

  const float4* xs4 = (const float4*)xs;
  #pragma unroll 4
  for (int it = 0; it < 16; ++it) {
    float4 n_fn[3];
    if (it < 15) {
      const int nfl = (it + 1) * 64 + lane;
      #pragma unroll
      for (int m = 0; m < 3; ++m) n_fn[m] = fn4[m][nfl];
    }
    const int fl = it * 64 + lane;
    #pragma unroll
    for (int tt = 0; tt < T; ++tt) {
      const float4 xv = xs4[tt * 1024 + fl];
      if (wave == 7)
        ssq[tt] = fmaf(xv.x, xv.x, fmaf(xv.y, xv.y, fmaf(xv.z, xv.z, fmaf(xv.w, xv.w, ssq[tt]))));
      #pragma unroll
      for (int m = 0; m < 3; ++m)
        acc[m][tt] = fmaf(xv.x, c_fn[m].x,
                     fmaf(xv.y, c_fn[m].y,
                     fmaf(xv.z, c_fn[m].z,
                     fmaf(xv.w, c_fn[m].w, acc[m][tt]))));
    }
    #pragma unroll
    for (int m = 0; m < 3; ++m) c_fn[m] = n_fn[m];
  }

  // ---- cross-lane reduction (12 values/wave; + 4 ssq on wave 7) ----
  #pragma unroll
  for (int m = 0; m < 3; ++m)
    #pragma unroll
    for (int tt = 0; tt < T; ++tt) {
      float v = acc[m][tt];
      #pragma unroll
      for (int off = 32; off > 0; off >>= 1) v += __shfl_xor(v, off, 64);
      if (lane == 0) w_s[mb + m][tt] = v;
    }
  if (wave == 7) {
    #pragma unroll
    for (int tt = 0; tt < T; ++tt) {
      float v = ssq[tt];
      #pragma unroll
      for (int off = 32; off > 0; off >>= 1) v += __shfl_xor(v, off, 64);
      if (lane == 0) ss_s[tt] = v;
    }
  }
  __syncthreads();

  // ---- Phase C: wave w (w<4) does token w; 16-lane shuffle sinkhorn, rcp not div.
  //      All 64 lanes compute (4 redundant copies); lanes<16 write. ----
  if (wave < T) {
    const int tt = wave;
    const int e  = lane & 15;          // i*4 + j
    const float rs = rsqrtf(ss_s[tt] * (1.0f / DDIM) + NORM_EPS_F);
    const float s0 = hc_scale[0], s1 = hc_scale[1], s2 = hc_scale[2];

    float h = w_s[8 + e][tt] * rs * s2 + hc_base[8 + e];
    // softmax over j (quad shuffles) + eps
    float mx = fmaxf(h, __shfl_xor(h, 1, 4));
    mx = fmaxf(mx, __shfl_xor(mx, 2, 4));
    float ex = expf(h - mx);
    float sm = ex + __shfl_xor(ex, 1, 4);
    sm += __shfl_xor(sm, 2, 4);
    h = ex * frcp(sm) + HC_EPS_F;
    // column normalize (sum over i: xor 4,8 within 16)
    float cs = h + __shfl_xor(h, 4, 16);
    cs += __shfl_xor(cs, 8, 16);
    h *= frcp(cs + HC_EPS_F);
    #pragma unroll 1
    for (int itn = 0; itn < 19; ++itn) {
      float rsum = h + __shfl_xor(h, 1, 4);
      rsum += __shfl_xor(rsum, 2, 4);
      h *= frcp(rsum + HC_EPS_F);
      float csum = h + __shfl_xor(h, 4, 16);
      csum += __shfl_xor(csum, 8, 16);
      h *= frcp(csum + HC_EPS_F);
    }
    if (lane < 16) hres_s[tt][e >> 2][e & 3] = h;
    if (lane < NS) {
      const float wp = w_s[lane][tt] * rs;
      hpre_s[tt][lane] = frcp(1.0f + expf(-(wp * s0 + hc_base[lane]))) + HC_EPS_F;
      const float wq = w_s[NS + lane][tt] * rs;
      hpost_s[tt][lane] = 2.0f * frcp(1.0f + expf(-(wq * s1 + hc_base[NS + lane])));
    }
  }
  __syncthreads();

  // ---- Phase D: token tt = wave&3, h-half = wave>>2. x from LDS, 1KB stores ----
  {
    const int tt = wave & 3;
    const int hf = wave >> 2;
    float hp[NS], hq[NS], hr[NS][NS];
    #pragma unroll
    for (int i = 0; i < NS; ++i) {
      hp[i] = hpre_s[tt][i];
      hq[i] = hpost_s[tt][i];
      #pragma unroll
      for (int j = 0; j < NS; ++j) hr[i][j] = hres_s[tt][i][j];
    }
    float4* ob = (float4*)(out + (tok0 + tt) * NS * HDIM);
    #pragma unroll
    for (int c = 0; c < 2; ++c) {
      const int h4 = hf * 128 + c * 64 + lane;   // float4 index in [0,256)
      float4 xv[NS];
      #pragma unroll
      for (int i = 0; i < NS; ++i) xv[i] = xs4[tt * 1024 + i * 256 + h4];
      float4 y;
      y.x = hp[0]*xv[0].x + hp[1]*xv[1].x + hp[2]*xv[2].x + hp[3]*xv[3].x;
      y.y = hp[0]*xv[0].y + hp[1]*xv[1].y + hp[2]*xv[2].y + hp[3]*xv[3].y;
      y.z = hp[0]*xv[0].z + hp[1]*xv[1].z + hp[2]*xv[2].z + hp[3]*xv[3].z;
      y.w = hp[0]*xv[0].w + hp[1]*xv[1].w + hp[2]*xv[2].w + hp[3]*xv[3].w;
      #pragma unroll
      for (int n = 0; n < NS; ++n) {
        float4 o;
        o.x = hq[n]*y.x + hr[0][n]*xv[0].x + hr[1][n]*xv[1].x + hr[2][n]*xv[2].x + hr[3][n]*xv[3].x;
        o.y = hq[n]*y.y + hr[0][n]*xv[0].y + hr[1][n]*xv[1].y + hr[2][n]*xv[2].y + hr[3][n]*xv[3].y;
        o.z = hq[n]*y.z + hr[0][n]*xv[0].z + hr[1][n]*xv[1].z + hr[2][n]*xv[2].z + hr[3][n]*xv[3].z;
        o.w = hq[n]*y.w + hr[0][n]*xv[0].w + hr[1][n]*xv[1].w + hr[2][n]*xv[2].w + hr[3][n]*xv[3].w;
        ob[n * 256 + h4] = o;
      }
    }
  }
}

extern "C" void kernel_launch(void* const* d_in, const int* in_sizes, int n_in,
                              void* d_out, int out_size, void* d_ws, size_t ws_size,
                              hipStream_t stream) {
  const float* x        = (const float*)d_in[0];
  const float* hc_fn    = (const float*)d_in[1];
  const float* hc_scale = (const float*)d_in[2];
  const float* hc_base  = (const float*)d_in[3];
  float* out = (float*)d_out;

  const int ntok = in_sizes[0] / DDIM;   // B*S = 8192
  const int grid = ntok / T;             // 2048
  mhc_fused<<<grid, NTH, 0, stream>>>(x, hc_fn, hc_scale, hc_base, out);
}

// Round 5
// 112.148 us; speedup vs baseline: 1.2554x; 1.0059x over previous
//
#include <hip/hip_runtime.h>
#include <math.h>

#define NS 4
#define HDIM 1024
#define DDIM 4096           // NS*HDIM
#define T1 8                // tokens per block in kernel 1
#define HC_EPS_F 1e-6f
#define NORM_EPS_F 1e-6f

__device__ __forceinline__ void gload_lds16(const float* g, float* l) {
  __builtin_amdgcn_global_load_lds(
      (const __attribute__((address_space(1))) void*)g,
      (__attribute__((address_space(3))) void*)l, 16, 0, 0);
}
__device__ __forceinline__ float frcp(float v) { return __builtin_amdgcn_rcpf(v); }

// ===================== Kernel 1: weights + sinkhorn -> gates =====================
// gates[token][24]: [0..3]=h_pre, [4..7]=h_post, [8..23]=h_res (i*4+j)
__launch_bounds__(256, 3)
__global__ void mhc_weights(const float* __restrict__ x,
                            const float* __restrict__ hc_fn,
                            const float* __restrict__ hc_scale,
                            const float* __restrict__ hc_base,
                            float* __restrict__ gates) {
  __shared__ float xs[2][T1][256];     // 2 x 8KB double buffer (256 floats/token)
  __shared__ float w_s[25][T1];        // 24 weights + ssq per token

  const int tid  = threadIdx.x;
  const int lane = tid & 63;
  const int wave = tid >> 6;
  const long long tok0 = (long long)blockIdx.x * T1;
  const float* xg  = x + tok0 * DDIM;
  const float* xw0 = xg + (2 * wave) * DDIM;       // wave stages tokens 2w, 2w+1
  const float* xw1 = xg + (2 * wave + 1) * DDIM;

  // stage chunk 0 (d in [0,256)) of both tokens; LDS dst wave-uniform + lane*16
  gload_lds16(xw0 + lane * 4, &xs[0][2 * wave][0]);
  gload_lds16(xw1 + lane * 4, &xs[0][2 * wave + 1][0]);

  // wave owns m in [6w, 6w+6)
  const int mb = wave * 6;
  const float4* fn4[6];
  #pragma unroll
  for (int m = 0; m < 6; ++m)
    fn4[m] = (const float4*)(hc_fn + (long long)(mb + m) * DDIM);
  float4 c_fn[6];
  #pragma unroll
  for (int m = 0; m < 6; ++m) c_fn[m] = fn4[m][lane];

  float acc[6][T1];
  float ssq[T1];
  #pragma unroll
  for (int m = 0; m < 6; ++m)
    #pragma unroll
    for (int tt = 0; tt < T1; ++tt) acc[m][tt] = 0.f;
  #pragma unroll
  for (int tt = 0; tt < T1; ++tt) ssq[tt] = 0.f;

  __syncthreads();                     // chunk 0 staged (vmcnt drained)

  // ---- 2-phase pipeline over 16 chunks of 256 floats ----
  int buf = 0;
  for (int it = 0; it < 16; ++it) {
    float4 n_fn[6];
    if (it < 15) {
      const int off = (it + 1) * 256 + lane * 4;
      gload_lds16(xw0 + off, &xs[buf ^ 1][2 * wave][0]);     // prefetch next chunk
      gload_lds16(xw1 + off, &xs[buf ^ 1][2 * wave + 1][0]);
      const int nfl = (it + 1) * 64 + lane;
      #pragma unroll
      for (int m = 0; m < 6; ++m) n_fn[m] = fn4[m][nfl];
    }
    #pragma unroll
    for (int tt = 0; tt < T1; ++tt) {
      const float4 xv = ((const float4*)xs[buf][tt])[lane];
      if (wave == 3)
        ssq[tt] = fmaf(xv.x, xv.x, fmaf(xv.y, xv.y, fmaf(xv.z, xv.z, fmaf(xv.w, xv.w, ssq[tt]))));
      #pragma unroll
      for (int m = 0; m < 6; ++m)
        acc[m][tt] = fmaf(xv.x, c_fn[m].x,
                     fmaf(xv.y, c_fn[m].y,
                     fmaf(xv.z, c_fn[m].z,
                     fmaf(xv.w, c_fn[m].w, acc[m][tt]))));
    }
    #pragma unroll
    for (int m = 0; m < 6; ++m) c_fn[m] = n_fn[m];
    __syncthreads();                   // drains prefetch vmcnt; fences buf reuse
    buf ^= 1;
  }

  // ---- cross-lane reduction: 6 (+ssq) x 8 tokens per wave ----
  #pragma unroll
  for (int m = 0; m < 6; ++m)
    #pragma unroll
    for (int tt = 0; tt < T1; ++tt) {
      float v = acc[m][tt];
      #pragma unroll
      for (int off = 32; off > 0; off >>= 1) v += __shfl_xor(v, off, 64);
      if (lane == 0) w_s[mb + m][tt] = v;
    }
  if (wave == 3) {
    #pragma unroll
    for (int tt = 0; tt < T1; ++tt) {
      float v = ssq[tt];
      #pragma unroll
      for (int off = 32; off > 0; off >>= 1) v += __shfl_xor(v, off, 64);
      if (lane == 0) w_s[24][tt] = v;
    }
  }
  __syncthreads();

  // ---- sinkhorn + gates: waves 0-1, 16 lanes per token (4 tokens/wave) ----
  if (wave < 2) {
    const int tt = wave * 4 + (lane >> 4);
    const int e  = lane & 15;          // i*4 + j
    const float rs = rsqrtf(w_s[24][tt] * (1.0f / DDIM) + NORM_EPS_F);
    const float s0 = hc_scale[0], s1 = hc_scale[1], s2 = hc_scale[2];

    float h = w_s[8 + e][tt] * rs * s2 + hc_base[8 + e];
    // softmax over j (quad shuffles) + eps
    float mx = fmaxf(h, __shfl_xor(h, 1, 4));
    mx = fmaxf(mx, __shfl_xor(mx, 2, 4));
    float ex = expf(h - mx);
    float sm = ex + __shfl_xor(ex, 1, 4);
    sm += __shfl_xor(sm, 2, 4);
    h = ex * frcp(sm) + HC_EPS_F;
    // column normalize (sum over i: xor 4,8 within 16)
    float cs = h + __shfl_xor(h, 4, 16);
    cs += __shfl_xor(cs, 8, 16);
    h *= frcp(cs + HC_EPS_F);
    #pragma unroll 1
    for (int itn = 0; itn < 19; ++itn) {
      float rsum = h + __shfl_xor(h, 1, 4);
      rsum += __shfl_xor(rsum, 2, 4);
      h *= frcp(rsum + HC_EPS_F);
      float csum = h + __shfl_xor(h, 4, 16);
      csum += __shfl_xor(csum, 8, 16);
      h *= frcp(csum + HC_EPS_F);
    }
    float* g = gates + (tok0 + tt) * 24;
    g[8 + e] = h;
    if (e < NS) {
      const float wp = w_s[e][tt] * rs;
      g[e] = frcp(1.0f + expf(-(wp * s0 + hc_base[e]))) + HC_EPS_F;
      const float wq = w_s[NS + e][tt] * rs;
      g[NS + e] = 2.0f * frcp(1.0f + expf(-(wq * s1 + hc_base[NS + e])));
    }
  }
}

// ===================== Kernel 2: gates + x -> out (pure stream) =====================
__launch_bounds__(256, 8)
__global__ void mhc_out(const float* __restrict__ x,
                        const float* __restrict__ gates,
                        float* __restrict__ out) {
  const long long token = blockIdx.x;
  const int q = threadIdx.x;           // float4 index in [0,256)

  const float* g = gates + token * 24; // uniform address -> scalar loads
  float hp[NS], hq[NS], hr[NS][NS];
  #pragma unroll
  for (int i = 0; i < NS; ++i) {
    hp[i] = g[i];
    hq[i] = g[NS + i];
    #pragma unroll
    for (int j = 0; j < NS; ++j) hr[i][j] = g[8 + i * NS + j];
  }

  const float4* xb = (const float4*)(x + token * DDIM);
  float4 xv[NS];
  #pragma unroll
  for (int i = 0; i < NS; ++i) xv[i] = xb[i * 256 + q];

  float4 y;
  y.x = hp[0]*xv[0].x + hp[1]*xv[1].x + hp[2]*xv[2].x + hp[3]*xv[3].x;
  y.y = hp[0]*xv[0].y + hp[1]*xv[1].y + hp[2]*xv[2].y + hp[3]*xv[3].y;
  y.z = hp[0]*xv[0].z + hp[1]*xv[1].z + hp[2]*xv[2].z + hp[3]*xv[3].z;
  y.w = hp[0]*xv[0].w + hp[1]*xv[1].w + hp[2]*xv[2].w + hp[3]*xv[3].w;

  float4* ob = (float4*)(out + token * DDIM);
  #pragma unroll
  for (int n = 0; n < NS; ++n) {
    float4 o;
    o.x = hq[n]*y.x + hr[0][n]*xv[0].x + hr[1][n]*xv[1].x + hr[2][n]*xv[2].x + hr[3][n]*xv[3].x;
    o.y = hq[n]*y.y + hr[0][n]*xv[0].y + hr[1][n]*xv[1].y + hr[2][n]*xv[2].y + hr[3][n]*xv[3].y;
    o.z = hq[n]*y.z + hr[0][n]*xv[0].z + hr[1][n]*xv[1].z + hr[2][n]*xv[2].z + hr[3][n]*xv[3].z;
    o.w = hq[n]*y.w + hr[0][n]*xv[0].w + hr[1][n]*xv[1].w + hr[2][n]*xv[2].w + hr[3][n]*xv[3].w;
    ob[n * 256 + q] = o;
  }
}

extern "C" void kernel_launch(void* const* d_in, const int* in_sizes, int n_in,
                              void* d_out, int out_size, void* d_ws, size_t ws_size,
                              hipStream_t stream) {
  const float* x        = (const float*)d_in[0];
  const float* hc_fn    = (const float*)d_in[1];
  const float* hc_scale = (const float*)d_in[2];
  const float* hc_base  = (const float*)d_in[3];
  float* out   = (float*)d_out;
  float* gates = (float*)d_ws;         // needs ntok*24*4 = 786 KB

  const int ntok = in_sizes[0] / DDIM; // B*S = 8192
  mhc_weights<<<ntok / T1, 256, 0, stream>>>(x, hc_fn, hc_scale, hc_base, gates);
  mhc_out<<<ntok, 256, 0, stream>>>(x, gates, out);
}

// Round 7
// 107.312 us; speedup vs baseline: 1.3120x; 1.0451x over previous
//
#include <hip/hip_runtime.h>
#include <math.h>

#define NS 4
#define HDIM 1024
#define DDIM 4096           // NS*HDIM
#define TA 8                // tokens per block in mhc_gates
#define HC_EPS_F 1e-6f
#define NORM_EPS_F 1e-6f

__device__ __forceinline__ float frcp(float v) { return __builtin_amdgcn_rcpf(v); }

// ============ K1: dots + sinkhorn -> gates[tok][24]. No x-staging; one barrier. ============
// gates layout: [0..3]=h_pre, [4..7]=h_post, [8..23]=h_res (i*4+j)
__launch_bounds__(256, 3)
__global__ void mhc_gates(const float* __restrict__ x,
                          const float* __restrict__ hc_fn,
                          const float* __restrict__ hc_scale,
                          const float* __restrict__ hc_base,
                          float* __restrict__ gates) {
  __shared__ float w_s[25][TA];        // 24 weights + ssq per token (800 B)

  const int tid  = threadIdx.x;
  const int lane = tid & 63;
  const int wave = tid >> 6;
  const long long tok0 = (long long)blockIdx.x * TA;

  const float4* xb[TA];
  #pragma unroll
  for (int t = 0; t < TA; ++t)
    xb[t] = (const float4*)(x + (tok0 + t) * DDIM);

  const int mb = wave * 6;             // wave owns m in [6w, 6w+6)
  const float4* fn4[6];
  #pragma unroll
  for (int m = 0; m < 6; ++m)
    fn4[m] = (const float4*)(hc_fn + (long long)(mb + m) * DDIM);

  float acc[6][TA];
  float ssq[TA];
  #pragma unroll
  for (int m = 0; m < 6; ++m)
    #pragma unroll
    for (int t = 0; t < TA; ++t) acc[m][t] = 0.f;
  #pragma unroll
  for (int t = 0; t < TA; ++t) ssq[t] = 0.f;

  float4 c_fn[6];
  #pragma unroll
  for (int m = 0; m < 6; ++m) c_fn[m] = fn4[m][lane];

  for (int it = 0; it < 16; ++it) {
    const int fl = it * 64 + lane;
    float4 xv[TA];
    #pragma unroll
    for (int t = 0; t < TA; ++t) xv[t] = xb[t][fl];   // 8 independent loads in flight
    float4 n_fn[6];
    if (it < 15) {
      #pragma unroll
      for (int m = 0; m < 6; ++m) n_fn[m] = fn4[m][fl + 64];
    }
    #pragma unroll
    for (int t = 0; t < TA; ++t) {
      if (wave == 3)
        ssq[t] = fmaf(xv[t].x, xv[t].x, fmaf(xv[t].y, xv[t].y,
                 fmaf(xv[t].z, xv[t].z, fmaf(xv[t].w, xv[t].w, ssq[t]))));
      #pragma unroll
      for (int m = 0; m < 6; ++m)
        acc[m][t] = fmaf(xv[t].x, c_fn[m].x,
                    fmaf(xv[t].y, c_fn[m].y,
                    fmaf(xv[t].z, c_fn[m].z,
                    fmaf(xv[t].w, c_fn[m].w, acc[m][t]))));
    }
    if (it < 15) {
      #pragma unroll
      for (int m = 0; m < 6; ++m) c_fn[m] = n_fn[m];
    }
  }

  // butterfly reduce -> LDS (lane 0 of each wave writes its 6 m-rows)
  #pragma unroll
  for (int m = 0; m < 6; ++m)
    #pragma unroll
    for (int t = 0; t < TA; ++t) {
      float v = acc[m][t];
      #pragma unroll
      for (int off = 32; off > 0; off >>= 1) v += __shfl_xor(v, off, 64);
      if (lane == 0) w_s[mb + m][t] = v;
    }
  if (wave == 3) {
    #pragma unroll
    for (int t = 0; t < TA; ++t) {
      float v = ssq[t];
      #pragma unroll
      for (int off = 32; off > 0; off >>= 1) v += __shfl_xor(v, off, 64);
      if (lane == 0) w_s[24][t] = v;
    }
  }
  __syncthreads();

  // sinkhorn + gates on waves 0-1: 16 lanes per token, 4 tokens per wave
  if (wave < 2) {
    const int tt = wave * 4 + (lane >> 4);
    const int e  = lane & 15;          // i*4 + j
    const float rs = rsqrtf(w_s[24][tt] * (1.0f / DDIM) + NORM_EPS_F);
    const float s0 = hc_scale[0], s1 = hc_scale[1], s2 = hc_scale[2];

    float h = w_s[8 + e][tt] * rs * s2 + hc_base[8 + e];
    // row softmax over j (quad shuffles) + eps
    float mx = fmaxf(h, __shfl_xor(h, 1, 4));
    mx = fmaxf(mx, __shfl_xor(mx, 2, 4));
    float ex = expf(h - mx);
    float sm = ex + __shfl_xor(ex, 1, 4);
    sm += __shfl_xor(sm, 2, 4);
    h = ex * frcp(sm) + HC_EPS_F;
    // column normalize (sum over i: xor 4,8 within 16)
    float cs = h + __shfl_xor(h, 4, 16);
    cs += __shfl_xor(cs, 8, 16);
    h *= frcp(cs + HC_EPS_F);
    #pragma unroll 1
    for (int itn = 0; itn < 19; ++itn) {
      float rsum = h + __shfl_xor(h, 1, 4);
      rsum += __shfl_xor(rsum, 2, 4);
      h *= frcp(rsum + HC_EPS_F);
      float csum = h + __shfl_xor(h, 4, 16);
      csum += __shfl_xor(csum, 8, 16);
      h *= frcp(csum + HC_EPS_F);
    }
    float* g = gates + (tok0 + tt) * 24;
    g[8 + e] = h;
    if (e < NS) {
      const float wp = w_s[e][tt] * rs;
      g[e] = frcp(1.0f + expf(-(wp * s0 + hc_base[e]))) + HC_EPS_F;
      const float wq = w_s[NS + e][tt] * rs;
      g[NS + e] = 2.0f * frcp(1.0f + expf(-(wq * s1 + hc_base[NS + e])));
    }
  }
}

// ============ K2: gates + x -> out (pure stream, measured ~22us) ============
__launch_bounds__(256, 8)
__global__ void mhc_out(const float* __restrict__ x,
                        const float* __restrict__ gates,
                        float* __restrict__ out) {
  const long long token = blockIdx.x;
  const int q = threadIdx.x;           // float4 index in [0,256)

  const float* g = gates + token * 24; // uniform address -> scalar loads
  float hp[NS], hq[NS], hr[NS][NS];
  #pragma unroll
  for (int i = 0; i < NS; ++i) {
    hp[i] = g[i];
    hq[i] = g[NS + i];
    #pragma unroll
    for (int j = 0; j < NS; ++j) hr[i][j] = g[8 + i * NS + j];
  }

  const float4* xb = (const float4*)(x + token * DDIM);
  float4 xv[NS];
  #pragma unroll
  for (int i = 0; i < NS; ++i) xv[i] = xb[i * 256 + q];

  float4 y;
  y.x = hp[0]*xv[0].x + hp[1]*xv[1].x + hp[2]*xv[2].x + hp[3]*xv[3].x;
  y.y = hp[0]*xv[0].y + hp[1]*xv[1].y + hp[2]*xv[2].y + hp[3]*xv[3].y;
  y.z = hp[0]*xv[0].z + hp[1]*xv[1].z + hp[2]*xv[2].z + hp[3]*xv[3].z;
  y.w = hp[0]*xv[0].w + hp[1]*xv[1].w + hp[2]*xv[2].w + hp[3]*xv[3].w;

  float4* ob = (float4*)(out + token * DDIM);
  #pragma unroll
  for (int n = 0; n < NS; ++n) {
    float4 o;
    o.x = hq[n]*y.x + hr[0][n]*xv[0].x + hr[1][n]*xv[1].x + hr[2][n]*xv[2].x + hr[3][n]*xv[3].x;
    o.y = hq[n]*y.y + hr[0][n]*xv[0].y + hr[1][n]*xv[1].y + hr[2][n]*xv[2].y + hr[3][n]*xv[3].y;
    o.z = hq[n]*y.z + hr[0][n]*xv[0].z + hr[1][n]*xv[1].z + hr[2][n]*xv[2].z + hr[3][n]*xv[3].z;
    o.w = hq[n]*y.w + hr[0][n]*xv[0].w + hr[1][n]*xv[1].w + hr[2][n]*xv[2].w + hr[3][n]*xv[3].w;
    ob[n * 256 + q] = o;
  }
}

extern "C" void kernel_launch(void* const* d_in, const int* in_sizes, int n_in,
                              void* d_out, int out_size, void* d_ws, size_t ws_size,
                              hipStream_t stream) {
  const float* x        = (const float*)d_in[0];
  const float* hc_fn    = (const float*)d_in[1];
  const float* hc_scale = (const float*)d_in[2];
  const float* hc_base  = (const float*)d_in[3];
  float* out   = (float*)d_out;
  float* gates = (float*)d_ws;         // ntok*24*4 = 786 KB (proven within ws_size)

  const int ntok = in_sizes[0] / DDIM; // B*S = 8192
  mhc_gates<<<ntok / TA, 256, 0, stream>>>(x, hc_fn, hc_scale, hc_base, gates);
  mhc_out<<<ntok, 256, 0, stream>>>(x, gates, out);
}